// Round 2
// baseline (107.016 us; speedup 1.0000x reference)
//
#include <hip/hip_runtime.h>

#define GAMMA 0.99f
constexpr int T_DIM = 128;
constexpr int B_DIM = 512;
constexpr int Q_DIM = 50;
constexpr int TRET  = 127;              // loss rows per b (t = 0..126)
constexpr int SLOT  = 52;               // LDS row stride (208 B, 16B-aligned)
constexpr int NPAIR = TRET * (Q_DIM/2); // 3175 (t, j-pair) slots per b
constexpr int ASLOT = 64 * (Q_DIM/2);   // 1600 pair-slots in rows 0..63
constexpr int KEEP  = -1;

// ---------------------------------------------------------------------------
// Fused kernel: one 1024-thread block per b (512 blocks = exactly 2/CU).
// v3 changes (issue-bound model; phase 3 = 10.6 us VALU floor, attack the
// ~8 us of phase-1 barriers + exposed global latency instead):
//  - Phase 0: prefetch ALL `value` float2s for this thread's 4 (t,j) slots
//    at kernel top (addresses scan-independent) -> phase-3 latency hidden.
//  - Phase 1: single-wave shfl scan. Lane l holds elements t=l and t=l+64
//    (strided), 6 shfl rounds + 1 local round reproduce the EXACT
//    Hillis-Steele schedule/fma forms of v2 -> bitwise-identical
//    alpha/beta/anchor; 7 block barriers -> 1.
//  - Phase 2 split (T14): stage rows 0..63; ISSUE tv loads for rows 64..126
//    into regs; barrier; compute rows 0..63 while those loads fly; write
//    rows 64..126; barrier; compute rows 64..126.
// Per-(t,j) accumulation order identical to v2 -> absmax must stay 0.0.
// ---------------------------------------------------------------------------
__global__ void __launch_bounds__(1024, 8) fused_kernel(
    const float* __restrict__ reward,
    const int*   __restrict__ step_type,
    const float* __restrict__ discount,
    const float* __restrict__ value,
    const float* __restrict__ tv,
    float*       __restrict__ out) {
  __shared__ __align__(16) float sret[TRET * SLOT];   // 26.4 KB
  __shared__ __align__(16) float pacc[TRET * SLOT];   // 26.4 KB
  __shared__ float s_alpha[TRET], s_beta[TRET];
  __shared__ int   s_anchor[TRET];

  const int tid = threadIdx.x;
  const int b   = blockIdx.x;

  // ---- phase 0: slot geometry + value prefetch (scan-independent) ----
  // A slots: sa0 = tid (<1600 always), sa1 = tid+1024 (if tid<576)
  // B slots: sb0 = 1600+tid (<3175 always), sb1 = 2624+tid (if tid<551)
  const int  sa0 = tid,         sa1 = tid + 1024;
  const int  sb0 = 1600 + tid,  sb1 = 2624 + tid;
  const bool ha1 = (sa1 < ASLOT);   // tid < 576
  const bool hb1 = (sb1 < NPAIR);   // tid < 551

  auto vaddr = [&](int s) {
    const int t  = s / 25;
    const int j0 = (s - t * 25) * 2;
    return (t * B_DIM + b) * Q_DIM + j0;
  };
  float2 va0, va1, vb0, vb1;
  va0 = *reinterpret_cast<const float2*>(&value[vaddr(sa0)]);
  vb0 = *reinterpret_cast<const float2*>(&value[vaddr(sb0)]);
  if (ha1) va1 = *reinterpret_cast<const float2*>(&value[vaddr(sa1)]);
  if (hb1) vb1 = *reinterpret_cast<const float2*>(&value[vaddr(sb1)]);
  if (tid == 1023) out[TRET * B_DIM + b] = 0.0f;   // required zero row t=127

  // ---- phase 1: single-wave scan (wave 0; lane l owns t=l and t=l+64) ----
  if (tid < 64) {
    const int t0 = tid, t1 = tid + 64;
    // element t0 (t0 <= 63 < 127: always a real element)
    const bool  last0 = (step_type[t0 * B_DIM + b] == 2);
    const float d0    = GAMMA * discount[(t0 + 1) * B_DIM + b];
    const float r0    = reward[(t0 + 1) * B_DIM + b];
    float p0  = last0 ? 0.0f : d0;
    float qa0 = last0 ? 1.0f : 0.0f;
    float qb0 = last0 ? 0.0f : r0;
    int   nv0 = last0 ? t0   : KEEP;
    // element t1 (identity when t1 == 127)
    float p1 = 1.0f, qa1 = 0.0f, qb1 = 0.0f; int nv1 = KEEP;
    if (t1 < TRET) {
      const bool  last1 = (step_type[t1 * B_DIM + b] == 2);
      const float d1    = GAMMA * discount[(t1 + 1) * B_DIM + b];
      const float r1    = reward[(t1 + 1) * B_DIM + b];
      p1  = last1 ? 0.0f : d1;
      qa1 = last1 ? 1.0f : 0.0f;
      qb1 = last1 ? 0.0f : r1;
      nv1 = last1 ? t1   : KEEP;
    }
    // rounds off = 1..32: partner via shfl.  Element t0+off lives at lane
    // tid+off slot0 when tid+off<64, else lane tid+off-64 slot1 -> the
    // wrapped __shfl(v1, tid+off, 64) delivers it.  Element t1+off is
    // lane tid+off slot1, valid iff tid+off<64 (else index > 127).
#pragma unroll
    for (int off = 1; off < 64; off <<= 1) {
      const int   src  = tid + off;
      const float xp0  = __shfl(p0,  src, 64), xp1  = __shfl(p1,  src, 64);
      const float xqa0 = __shfl(qa0, src, 64), xqa1 = __shfl(qa1, src, 64);
      const float xqb0 = __shfl(qb0, src, 64), xqb1 = __shfl(qb1, src, 64);
      const int   xnv0 = __shfl(nv0, src, 64), xnv1 = __shfl(nv1, src, 64);
      const bool  inl  = (src < 64);
      const float pp  = inl ? xp0  : xp1;
      const float pqa = inl ? xqa0 : xqa1;
      const float pqb = inl ? xqb0 : xqb1;
      const int   pnv = inl ? xnv0 : xnv1;
      qa0 = fmaf(p0, pqa, qa0);         // self is the OUTER map (same as v2)
      qb0 = fmaf(p0, pqb, qb0);
      p0  = p0 * pp;
      nv0 = (nv0 == KEEP) ? pnv : nv0;
      if (inl) {                        // slot1 active iff t1+off < 128
        qa1 = fmaf(p1, xqa1, qa1);
        qb1 = fmaf(p1, xqb1, qb1);
        p1  = p1 * xp1;
        nv1 = (nv1 == KEEP) ? xnv1 : nv1;
      }
    }
    // round off = 64: slot0 composes with own slot1 (always active);
    // slot1's partner index t1+64 > 127 -> inactive (matches v2).
    qa0 = fmaf(p0, qa1, qa0);
    qb0 = fmaf(p0, qb1, qb0);
    p0  = p0 * p1;
    nv0 = (nv0 == KEEP) ? nv1 : nv0;

    s_alpha[t0]  = p0 + qa0;            // applied to (a=1, be=0, n=127)
    s_beta[t0]   = qb0;
    s_anchor[t0] = (nv0 == KEEP) ? TRET : nv0;
    if (t1 < TRET) {
      s_alpha[t1]  = p1 + qa1;
      s_beta[t1]   = qb1;
      s_anchor[t1] = (nv1 == KEEP) ? TRET : nv1;
    }
  }
  __syncthreads();                      // B1: scan results visible

  // ---- phase 2B-issue: tv loads for rows 64..126 into regs (fly during
  //      phase 2A + 3A) ----
  int bt0, bi0, bt1 = 0, bi1 = 0;
  float bA0, bB0, bA1 = 0.0f, bB1 = 0.0f;
  float2 btv0, btv1;
  {
    bt0 = sb0 / 25; bi0 = (sb0 - bt0 * 25) * 2;
    bA0 = s_alpha[bt0]; bB0 = s_beta[bt0];
    btv0 = *reinterpret_cast<const float2*>(
        &tv[(s_anchor[bt0] * B_DIM + b) * Q_DIM + bi0]);
  }
  if (hb1) {
    bt1 = sb1 / 25; bi1 = (sb1 - bt1 * 25) * 2;
    bA1 = s_alpha[bt1]; bB1 = s_beta[bt1];
    btv1 = *reinterpret_cast<const float2*>(
        &tv[(s_anchor[bt1] * B_DIM + b) * Q_DIM + bi1]);
  }

  // ---- phase 2A: stage rows 0..63 ----
  auto stage = [&](int e) {
    const int t = e / 25;
    const int i = (e - t * 25) * 2;
    const float a  = s_alpha[t];
    const float be = s_beta[t];
    const float2 tvv = *reinterpret_cast<const float2*>(
        &tv[(s_anchor[t] * B_DIM + b) * Q_DIM + i]);
    *reinterpret_cast<float2*>(&sret[t * SLOT + i]) =
        make_float2(fmaf(a, tvv.x, be), fmaf(a, tvv.y, be));
  };
  stage(sa0);
  if (ha1) stage(sa1);
  __syncthreads();                      // B2: rows 0..63 visible

  // ---- phase 3 compute: identical math/order to v2 (bitwise) ----
  auto compute_slot = [&](int s, float2 vv) {
    const int t  = s / 25;
    const int j0 = (s - t * 25) * 2;
    const float ta0 = ((float)j0 + 0.5f) * (1.0f / Q_DIM) - 0.5f;
    const float ta1 = ((float)j0 + 1.5f) * (1.0f / Q_DIM) - 0.5f;
    const float* rp = &sret[t * SLOT];
    float s1a = 0.0f, s2a = 0.0f, s1b = 0.0f, s2b = 0.0f;
    auto pair2 = [&](float reti) {
      { const float d = reti - vv.x;
        const float c = __builtin_amdgcn_fmed3f(d, -1.0f, 1.0f);
        const float e = fmaf(-0.5f, c, d);
        s1a = fmaf(e, c, s1a);          // sum huber(d)
        s2a = fmaf(e, fabsf(c), s2a); } // sum sgn(d)*huber(d)
      { const float d = reti - vv.y;
        const float c = __builtin_amdgcn_fmed3f(d, -1.0f, 1.0f);
        const float e = fmaf(-0.5f, c, d);
        s1b = fmaf(e, c, s1b);
        s2b = fmaf(e, fabsf(c), s2b); }
    };
#pragma unroll
    for (int i0 = 0; i0 < 48; i0 += 4) {
      const float4 rr = *reinterpret_cast<const float4*>(rp + i0);
      pair2(rr.x); pair2(rr.y); pair2(rr.z); pair2(rr.w);
    }
    {
      const float2 rr = *reinterpret_cast<const float2*>(rp + 48);
      pair2(rr.x); pair2(rr.y);
    }
    *reinterpret_cast<float2*>(&pacc[t * SLOT + j0]) =
        make_float2(fmaf(ta0, s2a, 0.5f * s1a), fmaf(ta1, s2b, 0.5f * s1b));
  };

  // phase 3A: rows 0..63 (B-row tv loads in flight underneath)
  compute_slot(sa0, va0);
  if (ha1) compute_slot(sa1, va1);

  // phase 2B-write: rows 64..126 (loads long since landed)
  *reinterpret_cast<float2*>(&sret[bt0 * SLOT + bi0]) =
      make_float2(fmaf(bA0, btv0.x, bB0), fmaf(bA0, btv0.y, bB0));
  if (hb1)
    *reinterpret_cast<float2*>(&sret[bt1 * SLOT + bi1]) =
        make_float2(fmaf(bA1, btv1.x, bB1), fmaf(bA1, btv1.y, bB1));
  __syncthreads();                      // B3: rows 64..126 visible

  // phase 3B: rows 64..126
  compute_slot(sb0, vb0);
  if (hb1) compute_slot(sb1, vb1);
  __syncthreads();                      // B4: all pacc visible

  // ---- phase 4: per-row reduce; wave w handles rows 8w..8w+7 ----
  const int w    = tid >> 6;
  const int lane = tid & 63;
#pragma unroll
  for (int k = 0; k < 8; ++k) {
    const int t = w * 8 + k;
    if (t < TRET) {
      float x = (lane < Q_DIM) ? pacc[t * SLOT + lane] : 0.0f;
#pragma unroll
      for (int off = 32; off > 0; off >>= 1)
        x += __shfl_xor(x, off, 64);
      if (lane == 0) out[t * B_DIM + b] = x * (1.0f / Q_DIM);
    }
  }
}

// ---------------------------------------------------------------------------
extern "C" void kernel_launch(void* const* d_in, const int* in_sizes, int n_in,
                              void* d_out, int out_size, void* d_ws, size_t ws_size,
                              hipStream_t stream) {
  const float* reward       = (const float*)d_in[0];
  const int*   step_type    = (const int*)  d_in[1];
  const float* discount     = (const float*)d_in[2];
  const float* value        = (const float*)d_in[3];
  const float* target_value = (const float*)d_in[4];
  float* out = (float*)d_out;

  fused_kernel<<<B_DIM, 1024, 0, stream>>>(reward, step_type, discount,
                                           value, target_value, out);
}

// Round 3
// 105.738 us; speedup vs baseline: 1.0121x; 1.0121x over previous
//
#include <hip/hip_runtime.h>

#define GAMMA 0.99f
constexpr int T_DIM = 128;
constexpr int B_DIM = 512;
constexpr int Q_DIM = 50;
constexpr int TRET  = 127;              // loss rows per b (t = 0..126)
constexpr int SLOT  = 52;               // LDS row stride (208 B, 16B-aligned)
constexpr int NPAIR = TRET * (Q_DIM/2); // 3175 (t, j-pair) slots per b
constexpr int KEEP  = -1;

// ---------------------------------------------------------------------------
// v4: one 1024-thread block per b (512 blocks = 2/CU, 32 waves).
//  - Phase 1: single-wave shfl scan (HW-verified bitwise in v3, absmax 0.0).
//  - Phase 2: STATIC slot schedule {tid, tid+1024, tid+2048, [tid+3072]}.
//    All 4 tv gathers issued together, then all 4 value loads issued
//    (consumed right after B2 -> ~1-barrier lifetime, no spill), then the
//    4 LDS writes. No dynamic-trip loops -> compiler can batch the loads
//    instead of exposing one HBM latency per lockstep iteration.
//  - Phase 3: compute the same 4 slots with prefetched value pairs.
//  - NO values live across more than one barrier (v3's 20 MiB scratch-spill
//    regression removed).
// Per-(t,j) accumulation order identical to v2/v3 -> absmax must stay 0.0.
// ---------------------------------------------------------------------------
__global__ void __launch_bounds__(1024, 8) fused_kernel(
    const float* __restrict__ reward,
    const int*   __restrict__ step_type,
    const float* __restrict__ discount,
    const float* __restrict__ value,
    const float* __restrict__ tv,
    float*       __restrict__ out) {
  __shared__ __align__(16) float sret[TRET * SLOT];   // 26.4 KB
  __shared__ __align__(16) float pacc[TRET * SLOT];   // 26.4 KB
  __shared__ float s_alpha[TRET], s_beta[TRET];
  __shared__ int   s_anchor[TRET];

  const int tid = threadIdx.x;
  const int b   = blockIdx.x;

  if (tid == 1023) out[TRET * B_DIM + b] = 0.0f;   // required zero row t=127

  // ---- phase 1: single-wave scan (wave 0; lane l owns t=l and t=l+64) ----
  if (tid < 64) {
    const int t0 = tid, t1 = tid + 64;
    const bool  last0 = (step_type[t0 * B_DIM + b] == 2);
    const float d0    = GAMMA * discount[(t0 + 1) * B_DIM + b];
    const float r0    = reward[(t0 + 1) * B_DIM + b];
    float p0  = last0 ? 0.0f : d0;
    float qa0 = last0 ? 1.0f : 0.0f;
    float qb0 = last0 ? 0.0f : r0;
    int   nv0 = last0 ? t0   : KEEP;
    float p1 = 1.0f, qa1 = 0.0f, qb1 = 0.0f; int nv1 = KEEP;
    if (t1 < TRET) {
      const bool  last1 = (step_type[t1 * B_DIM + b] == 2);
      const float d1    = GAMMA * discount[(t1 + 1) * B_DIM + b];
      const float r1    = reward[(t1 + 1) * B_DIM + b];
      p1  = last1 ? 0.0f : d1;
      qa1 = last1 ? 1.0f : 0.0f;
      qb1 = last1 ? 0.0f : r1;
      nv1 = last1 ? t1   : KEEP;
    }
#pragma unroll
    for (int off = 1; off < 64; off <<= 1) {
      const int   src  = tid + off;
      const float xp0  = __shfl(p0,  src, 64), xp1  = __shfl(p1,  src, 64);
      const float xqa0 = __shfl(qa0, src, 64), xqa1 = __shfl(qa1, src, 64);
      const float xqb0 = __shfl(qb0, src, 64), xqb1 = __shfl(qb1, src, 64);
      const int   xnv0 = __shfl(nv0, src, 64), xnv1 = __shfl(nv1, src, 64);
      const bool  inl  = (src < 64);
      const float pp  = inl ? xp0  : xp1;
      const float pqa = inl ? xqa0 : xqa1;
      const float pqb = inl ? xqb0 : xqb1;
      const int   pnv = inl ? xnv0 : xnv1;
      qa0 = fmaf(p0, pqa, qa0);         // self is the OUTER map (as v2)
      qb0 = fmaf(p0, pqb, qb0);
      p0  = p0 * pp;
      nv0 = (nv0 == KEEP) ? pnv : nv0;
      if (inl) {                        // slot1 active iff t1+off < 128
        qa1 = fmaf(p1, xqa1, qa1);
        qb1 = fmaf(p1, xqb1, qb1);
        p1  = p1 * xp1;
        nv1 = (nv1 == KEEP) ? xnv1 : nv1;
      }
    }
    // final round off = 64: slot0 composes with own slot1
    qa0 = fmaf(p0, qa1, qa0);
    qb0 = fmaf(p0, qb1, qb0);
    p0  = p0 * p1;
    nv0 = (nv0 == KEEP) ? nv1 : nv0;

    s_alpha[t0]  = p0 + qa0;            // applied to (a=1, be=0, n=127)
    s_beta[t0]   = qb0;
    s_anchor[t0] = (nv0 == KEEP) ? TRET : nv0;
    if (t1 < TRET) {
      s_alpha[t1]  = p1 + qa1;
      s_beta[t1]   = qb1;
      s_anchor[t1] = (nv1 == KEEP) ? TRET : nv1;
    }
  }
  __syncthreads();                      // B1: scan results visible

  // ---- phase 2: static 4-slot schedule; batch-issue all global loads ----
  const int e0 = tid, e1 = tid + 1024, e2 = tid + 2048, e3 = tid + 3072;
  const bool h3 = (e3 < NPAIR);         // tid < 103
  const int t0 = e0 / 25, i0 = (e0 - t0 * 25) * 2;
  const int t1 = e1 / 25, i1 = (e1 - t1 * 25) * 2;
  const int t2 = e2 / 25, i2 = (e2 - t2 * 25) * 2;
  const int t3 = h3 ? e3 / 25 : 0;
  const int i3 = h3 ? (e3 - t3 * 25) * 2 : 0;

  const float A0 = s_alpha[t0], Be0 = s_beta[t0];
  const float A1 = s_alpha[t1], Be1 = s_beta[t1];
  const float A2 = s_alpha[t2], Be2 = s_beta[t2];
  const float A3 = s_alpha[t3], Be3 = s_beta[t3];
  const int   n0 = s_anchor[t0], n1 = s_anchor[t1];
  const int   n2 = s_anchor[t2], n3 = s_anchor[t3];

  // issue the 4 tv gathers back-to-back
  const float2 g0 = *reinterpret_cast<const float2*>(&tv[(n0 * B_DIM + b) * Q_DIM + i0]);
  const float2 g1 = *reinterpret_cast<const float2*>(&tv[(n1 * B_DIM + b) * Q_DIM + i1]);
  const float2 g2 = *reinterpret_cast<const float2*>(&tv[(n2 * B_DIM + b) * Q_DIM + i2]);
  float2 g3 = make_float2(0.f, 0.f);
  if (h3) g3 = *reinterpret_cast<const float2*>(&tv[(n3 * B_DIM + b) * Q_DIM + i3]);

  // issue the 4 value loads (consumed just after B2 -> one-barrier lifetime)
  const float2 v0 = *reinterpret_cast<const float2*>(&value[(t0 * B_DIM + b) * Q_DIM + i0]);
  const float2 v1 = *reinterpret_cast<const float2*>(&value[(t1 * B_DIM + b) * Q_DIM + i1]);
  const float2 v2 = *reinterpret_cast<const float2*>(&value[(t2 * B_DIM + b) * Q_DIM + i2]);
  float2 v3 = make_float2(0.f, 0.f);
  if (h3) v3 = *reinterpret_cast<const float2*>(&value[(t3 * B_DIM + b) * Q_DIM + i3]);

  // LDS writes
  *reinterpret_cast<float2*>(&sret[t0 * SLOT + i0]) =
      make_float2(fmaf(A0, g0.x, Be0), fmaf(A0, g0.y, Be0));
  *reinterpret_cast<float2*>(&sret[t1 * SLOT + i1]) =
      make_float2(fmaf(A1, g1.x, Be1), fmaf(A1, g1.y, Be1));
  *reinterpret_cast<float2*>(&sret[t2 * SLOT + i2]) =
      make_float2(fmaf(A2, g2.x, Be2), fmaf(A2, g2.y, Be2));
  if (h3)
    *reinterpret_cast<float2*>(&sret[t3 * SLOT + i3]) =
        make_float2(fmaf(A3, g3.x, Be3), fmaf(A3, g3.y, Be3));
  __syncthreads();                      // B2: all ret rows visible

  // ---- phase 3: compute the same 4 slots (math/order identical to v2) ----
  auto compute_slot = [&](int t, int j0, float2 vv) {
    const float ta0 = ((float)j0 + 0.5f) * (1.0f / Q_DIM) - 0.5f;
    const float ta1 = ((float)j0 + 1.5f) * (1.0f / Q_DIM) - 0.5f;
    const float* rp = &sret[t * SLOT];
    float s1a = 0.0f, s2a = 0.0f, s1b = 0.0f, s2b = 0.0f;
    auto pair2 = [&](float reti) {
      { const float d = reti - vv.x;
        const float c = __builtin_amdgcn_fmed3f(d, -1.0f, 1.0f);
        const float e = fmaf(-0.5f, c, d);
        s1a = fmaf(e, c, s1a);          // sum huber(d)
        s2a = fmaf(e, fabsf(c), s2a); } // sum sgn(d)*huber(d)
      { const float d = reti - vv.y;
        const float c = __builtin_amdgcn_fmed3f(d, -1.0f, 1.0f);
        const float e = fmaf(-0.5f, c, d);
        s1b = fmaf(e, c, s1b);
        s2b = fmaf(e, fabsf(c), s2b); }
    };
#pragma unroll
    for (int k = 0; k < 48; k += 4) {
      const float4 rr = *reinterpret_cast<const float4*>(rp + k);
      pair2(rr.x); pair2(rr.y); pair2(rr.z); pair2(rr.w);
    }
    {
      const float2 rr = *reinterpret_cast<const float2*>(rp + 48);
      pair2(rr.x); pair2(rr.y);
    }
    *reinterpret_cast<float2*>(&pacc[t * SLOT + j0]) =
        make_float2(fmaf(ta0, s2a, 0.5f * s1a), fmaf(ta1, s2b, 0.5f * s1b));
  };

  compute_slot(t0, i0, v0);
  compute_slot(t1, i1, v1);
  compute_slot(t2, i2, v2);
  if (h3) compute_slot(t3, i3, v3);
  __syncthreads();                      // B3: all pacc visible

  // ---- phase 4: per-row reduce; wave w handles rows 8w..8w+7 ----
  const int w    = tid >> 6;
  const int lane = tid & 63;
#pragma unroll
  for (int k = 0; k < 8; ++k) {
    const int t = w * 8 + k;
    if (t < TRET) {
      float x = (lane < Q_DIM) ? pacc[t * SLOT + lane] : 0.0f;
#pragma unroll
      for (int off = 32; off > 0; off >>= 1)
        x += __shfl_xor(x, off, 64);
      if (lane == 0) out[t * B_DIM + b] = x * (1.0f / Q_DIM);
    }
  }
}

// ---------------------------------------------------------------------------
extern "C" void kernel_launch(void* const* d_in, const int* in_sizes, int n_in,
                              void* d_out, int out_size, void* d_ws, size_t ws_size,
                              hipStream_t stream) {
  const float* reward       = (const float*)d_in[0];
  const int*   step_type    = (const int*)  d_in[1];
  const float* discount     = (const float*)d_in[2];
  const float* value        = (const float*)d_in[3];
  const float* target_value = (const float*)d_in[4];
  float* out = (float*)d_out;

  fused_kernel<<<B_DIM, 1024, 0, stream>>>(reward, step_type, discount,
                                           value, target_value, out);
}

// Round 4
// 101.759 us; speedup vs baseline: 1.0517x; 1.0391x over previous
//
#include <hip/hip_runtime.h>

#define GAMMA 0.99f
constexpr int T_DIM = 128;
constexpr int B_DIM = 512;
constexpr int Q_DIM = 50;
constexpr int TRET  = 127;              // loss rows per b (t = 0..126)
constexpr int SLOT  = 52;               // LDS row stride (208 B, 16B-aligned)
constexpr int NSLOT = TRET * Q_DIM;     // 6350 (row,j) slots per b
constexpr int KEEP  = -1;

// ---------------------------------------------------------------------------
// Fused kernel: one 1024-thread block per b (512 blocks = exactly 2/CU).
// Phase 1: segmented suffix scan of affine maps over t (threads 0..127,
//          Hillis-Steele, 7 rounds) -> alpha/beta/anchor in LDS.
//          ret[t,q] = alpha[t]*tv[anchor[t],b,q] + beta[t].
// Phase 2: stage all 127 ret rows for this b into LDS.
// Phase 3: pair compute, one (t,j) column per slot; 5-op verified math:
//          d = ret_i - v; c = med3(d,-1,1); e = d - 0.5c
//          sum w*h = 0.5*sum(e*c) + (tau_j-0.5)*sum(e*|c|)
// Phase 4: per-row wave reduce -> out[t*B+b].  t=127 zero row written here.
// No workspace, no atomics, single graph node.
//
// Session conclusion (rounds 0-3): this variant is the best-measured
// (101.4 / 102.3 us).  dur_us decomposes as ~86 us of harness re-poison
// fills (2 x 256 MiB @ ~6.1 TB/s, serialized in-stream) + ~14-18 us kernel,
// whose phase-3 VALU-issue floor under the bitwise-exactness constraint is
// ~10.3 us (813M lane-ops / 2 issue/cyc/CU).  All v2-v4 restructurings
// (2-col LDS amortization, shfl scan, static load schedule) landed within
// the +/-2-3 us fill-noise band; the one resolvable change was the v3
// cross-barrier prefetch, which spilled 20 MiB to scratch and cost +4 us.
// ---------------------------------------------------------------------------
__global__ void __launch_bounds__(1024) fused_kernel(
    const float* __restrict__ reward,
    const int*   __restrict__ step_type,
    const float* __restrict__ discount,
    const float* __restrict__ value,
    const float* __restrict__ tv,
    float*       __restrict__ out) {
  __shared__ __align__(16) float sret[TRET * SLOT];   // 26.4 KB
  __shared__ float pacc[TRET * SLOT];                 // 26.4 KB
  __shared__ float sp[128], sqa[128], sqb[128];
  __shared__ int   snv[128];
  __shared__ float s_alpha[TRET], s_beta[TRET];
  __shared__ int   s_anchor[TRET];

  const int tid = threadIdx.x;
  const int b   = blockIdx.x;

  // ---- phase 1: scan (threads 0..127 active; all threads hit barriers) ----
  float p = 1.0f, qa = 0.0f, qb = 0.0f; int nv = KEEP;
  if (tid < TRET) {
    const bool  last = (step_type[tid * B_DIM + b] == 2);
    const float d    = GAMMA * discount[(tid + 1) * B_DIM + b];
    const float r    = reward[(tid + 1) * B_DIM + b];
    p  = last ? 0.0f : d;
    qa = last ? 1.0f : 0.0f;
    qb = last ? 0.0f : r;
    nv = last ? tid  : KEEP;
  } else if (tid == TRET) {
    out[TRET * B_DIM + b] = 0.0f;       // required zero row (t = 127)
  }
  if (tid < 128) { sp[tid] = p; sqa[tid] = qa; sqb[tid] = qb; snv[tid] = nv; }
  __syncthreads();

#pragma unroll
  for (int off = 1; off < 128; off <<= 1) {
    const bool act = (tid < 128) && (tid + off < 128);
    float p2 = 1.0f, qa2 = 0.0f, qb2 = 0.0f; int nv2 = KEEP;
    if (act) { p2 = sp[tid+off]; qa2 = sqa[tid+off]; qb2 = sqb[tid+off]; nv2 = snv[tid+off]; }
    __syncthreads();
    if (act) {
      qa = fmaf(p, qa2, qa);            // self is the OUTER map
      qb = fmaf(p, qb2, qb);
      p  = p * p2;
      nv = (nv == KEEP) ? nv2 : nv;
      sp[tid] = p; sqa[tid] = qa; sqb[tid] = qb; snv[tid] = nv;
    }
    __syncthreads();
  }

  if (tid < TRET) {
    s_alpha[tid]  = p + qa;             // applied to (a=1, be=0, n=127)
    s_beta[tid]   = qb;
    s_anchor[tid] = (nv == KEEP) ? TRET : nv;
  }
  __syncthreads();

  // ---- phase 2: stage all 127 ret rows for this b ----
  for (int e = tid; e < NSLOT; e += 1024) {
    const int t = e / Q_DIM;
    const int i = e - t * Q_DIM;
    const int n = s_anchor[t];
    sret[t * SLOT + i] =
        fmaf(s_alpha[t], tv[(n * B_DIM + b) * Q_DIM + i], s_beta[t]);
  }
  __syncthreads();

  // ---- phase 3: pair compute ----
  for (int s = tid; s < NSLOT; s += 1024) {
    const int t = s / Q_DIM;
    const int j = s - t * Q_DIM;
    const float v    = value[(t * B_DIM + b) * Q_DIM + j];   // coalesced
    const float tm05 = ((float)j + 0.5f) * (1.0f / Q_DIM) - 0.5f;
    const float* rp  = &sret[t * SLOT];

    float s1 = 0.0f, s2 = 0.0f;
    auto pair = [&](float reti) {
      const float d = reti - v;
      const float c = __builtin_amdgcn_fmed3f(d, -1.0f, 1.0f);
      const float e = fmaf(-0.5f, c, d);
      s1 = fmaf(e, c, s1);              // sum huber(d)
      s2 = fmaf(e, fabsf(c), s2);       // sum sgn(d)*huber(d)
    };
#pragma unroll
    for (int i0 = 0; i0 < 48; i0 += 4) {
      const float4 rr = *reinterpret_cast<const float4*>(rp + i0);
      pair(rr.x); pair(rr.y); pair(rr.z); pair(rr.w);
    }
    {
      const float2 rr = *reinterpret_cast<const float2*>(rp + 48);
      pair(rr.x); pair(rr.y);
    }
    pacc[t * SLOT + j] = fmaf(tm05, s2, 0.5f * s1);
  }
  __syncthreads();

  // ---- phase 4: per-row reduce; wave w handles rows 8w..8w+7 ----
  const int w    = tid >> 6;
  const int lane = tid & 63;
#pragma unroll
  for (int k = 0; k < 8; ++k) {
    const int t = w * 8 + k;
    if (t < TRET) {
      float x = (lane < Q_DIM) ? pacc[t * SLOT + lane] : 0.0f;
#pragma unroll
      for (int off = 32; off > 0; off >>= 1)
        x += __shfl_xor(x, off, 64);
      if (lane == 0) out[t * B_DIM + b] = x * (1.0f / Q_DIM);
    }
  }
}

// ---------------------------------------------------------------------------
extern "C" void kernel_launch(void* const* d_in, const int* in_sizes, int n_in,
                              void* d_out, int out_size, void* d_ws, size_t ws_size,
                              hipStream_t stream) {
  const float* reward       = (const float*)d_in[0];
  const int*   step_type    = (const int*)  d_in[1];
  const float* discount     = (const float*)d_in[2];
  const float* value        = (const float*)d_in[3];
  const float* target_value = (const float*)d_in[4];
  float* out = (float*)d_out;

  fused_kernel<<<B_DIM, 1024, 0, stream>>>(reward, step_type, discount,
                                           value, target_value, out);
}